// Round 1
// baseline (1576.642 us; speedup 1.0000x reference)
//
#include <hip/hip_runtime.h>
#include <math.h>

// AttentionSequencePoolingLayer (DIN): fp32 baseline, multi-kernel.
// z1 = [q,h,q-h,q*h] @ W1 + b1  ==  qW(b) + h@(Wb-Wc) + (q*h)@Wd, qW = b1 + q@(Wa+Wc)
// dice needs global per-feature mean/var over (B,T) -> partials + finalize kernels.
// K3: inverted mask (t<len -> 1e-9), softmax over T, out = score @ hist.

typedef float f4 __attribute__((ext_vector_type(4)));

#define B_   2048
#define T_   200
#define BT_  409600        // B_*T_
#define NB1  1600          // blocks in K1/K2 (256 rows each)

// ---------------- qW precompute: qW[b][j] = b1[j] + sum_k q[b][k]*(W1[k][j]+W1[128+k][j])
__global__ __launch_bounds__(256) void k_qw(
    const float* __restrict__ q, const float* __restrict__ W1,
    const float* __restrict__ b1, float* __restrict__ qW) {
  __shared__ float Wac[64 * 65];   // +1 pad: (k+lane)%32 -> 2-way, free
  __shared__ float ql[16 * 64];
  const int tid = threadIdx.x;
#pragma unroll
  for (int i = 0; i < 16; i++) {
    int idx = tid + 256 * i;
    int k = idx >> 6, j = idx & 63;
    Wac[k * 65 + j] = W1[k * 64 + j] + W1[(128 + k) * 64 + j];
  }
  const int b0 = blockIdx.x * 16;
#pragma unroll
  for (int i = 0; i < 4; i++) {
    int idx = tid + 256 * i;
    ql[idx] = q[(size_t)b0 * 64 + idx];
  }
  __syncthreads();
  const int wv = tid >> 6, lane = tid & 63;
#pragma unroll
  for (int ii = 0; ii < 4; ii++) {
    const int bl = wv * 4 + ii;
    float acc = b1[lane];
#pragma unroll 8
    for (int k = 0; k < 64; k++) acc += ql[bl * 64 + k] * Wac[k * 65 + lane];
    qW[(size_t)(b0 + bl) * 64 + lane] = acc;
  }
}

// ---------------- K1: z1[BT][64] = A[BT][128] @ Wcomb[128][64] + qW(b); stats1 partials
// A cols 0..63 = h, 64..127 = q*h ; Wcomb rows 0..63 = Wb-Wc, 64..127 = Wd
__global__ __launch_bounds__(256, 3) void k_gemm1(
    const float* __restrict__ q, const float* __restrict__ hist,
    const float* __restrict__ W1, const float* __restrict__ qW,
    float* __restrict__ z1, float* __restrict__ part1) {
  __shared__ float As[256 * 36];   // [row][kk], stride 36: b128-aligned, conflict-free reads
  __shared__ float Wl[32 * 64];    // W chunk [kk][j]
  const int tid = threadIdx.x;
  const int R0 = blockIdx.x * 256;
  const int wv = tid >> 6, ty = (tid >> 3) & 7, tx = tid & 7;
  const int j0 = tx * 8;
  const int rbase = 64 * wv + ty;  // thread rows: rbase + 8*i (stride-8 within wave)

  float acc[8][8];
#pragma unroll
  for (int i = 0; i < 8; i++) {
    int R = R0 + rbase + 8 * i;
    int b = (int)((unsigned)R / 200u);
    f4 qa = *(const f4*)(qW + (size_t)b * 64 + j0);
    f4 qb = *(const f4*)(qW + (size_t)b * 64 + j0 + 4);
#pragma unroll
    for (int jj = 0; jj < 4; jj++) { acc[i][jj] = qa[jj]; acc[i][4 + jj] = qb[jj]; }
  }

#pragma unroll
  for (int c = 0; c < 4; c++) {
    const int kb = (c & 1) * 32;   // source col base in hist/q
    const int kw = c * 32;         // combined-W row base
    __syncthreads();
    // stage W chunk (W1 is L2-hot, 64KB total)
#pragma unroll
    for (int i = 0; i < 8; i++) {
      int idx = tid + 256 * i;             // 2048
      int k = idx >> 6, j = idx & 63;      // k: 0..31
      int kg = kw + k;
      float w;
      if (kg < 64) w = W1[(64 + kg) * 64 + j] - W1[(128 + kg) * 64 + j];
      else         w = W1[(128 + kg) * 64 + j];   // rows 192.. of W1
      Wl[idx] = w;
    }
    // stage A chunk: 2048 float4 pieces
#pragma unroll
    for (int i = 0; i < 8; i++) {
      int p = tid + 256 * i;
      int row = p >> 3, k4 = p & 7;
      int R = R0 + row;
      f4 h4 = *(const f4*)(hist + (size_t)R * 64 + kb + 4 * k4);
      if (c >= 2) {
        int b = (int)((unsigned)R / 200u);
        f4 q4 = *(const f4*)(q + (size_t)b * 64 + kb + 4 * k4);
        h4 *= q4;
      }
      *(f4*)(As + row * 36 + 4 * k4) = h4;
    }
    __syncthreads();
#pragma unroll
    for (int k0 = 0; k0 < 32; k0 += 4) {
      f4 w0[4], w1[4];
#pragma unroll
      for (int dk = 0; dk < 4; dk++) {
        w0[dk] = *(const f4*)(Wl + (k0 + dk) * 64 + j0);
        w1[dk] = *(const f4*)(Wl + (k0 + dk) * 64 + j0 + 4);
      }
#pragma unroll
      for (int i = 0; i < 8; i++) {
        f4 a4 = *(const f4*)(As + (rbase + 8 * i) * 36 + k0);
#pragma unroll
        for (int dk = 0; dk < 4; dk++) {
#pragma unroll
          for (int jj = 0; jj < 4; jj++) {
            acc[i][jj]     += a4[dk] * w0[dk][jj];
            acc[i][4 + jj] += a4[dk] * w1[dk][jj];
          }
        }
      }
    }
  }

  // store z1
#pragma unroll
  for (int i = 0; i < 8; i++) {
    int R = R0 + rbase + 8 * i;
    f4 o0, o1;
#pragma unroll
    for (int jj = 0; jj < 4; jj++) { o0[jj] = acc[i][jj]; o1[jj] = acc[i][4 + jj]; }
    *(f4*)(z1 + (size_t)R * 64 + j0) = o0;
    *(f4*)(z1 + (size_t)R * 64 + j0 + 4) = o1;
  }

  // per-block stats (sum, sumsq per feature j over the 256 rows)
  float s8[8], q8[8];
#pragma unroll
  for (int jj = 0; jj < 8; jj++) { s8[jj] = 0.f; q8[jj] = 0.f; }
#pragma unroll
  for (int i = 0; i < 8; i++)
#pragma unroll
    for (int jj = 0; jj < 8; jj++) { float v = acc[i][jj]; s8[jj] += v; q8[jj] += v * v; }
  __syncthreads();
  float* red = As;   // reuse: [32][64] sums + [32][64] sqs = 16KB
  const int g = tid >> 3;
#pragma unroll
  for (int jj = 0; jj < 8; jj++) {
    red[g * 64 + j0 + jj] = s8[jj];
    red[2048 + g * 64 + j0 + jj] = q8[jj];
  }
  __syncthreads();
  if (tid < 64) {
    float s = 0.f, qq = 0.f;
    for (int gg = 0; gg < 32; gg++) { s += red[gg * 64 + tid]; qq += red[2048 + gg * 64 + tid]; }
    part1[(size_t)tid * NB1 + blockIdx.x] = s;
    part1[(size_t)(64 + tid) * NB1 + blockIdx.x] = qq;
  }
}

// ---------------- finalize: mean/rstd per feature from block partials
__global__ __launch_bounds__(256) void k_finalize(
    const float* __restrict__ part, float* __restrict__ statout,
    int nj, int nb, float invN) {
  const int j = blockIdx.x, tid = threadIdx.x;
  const float* ps = part + (size_t)j * nb;
  const float* pq = part + (size_t)(nj + j) * nb;
  float s = 0.f, qq = 0.f;
  for (int i = tid; i < nb; i += 256) { s += ps[i]; qq += pq[i]; }
#pragma unroll
  for (int off = 32; off > 0; off >>= 1) {
    s += __shfl_down(s, off);
    qq += __shfl_down(qq, off);
  }
  __shared__ float rs[4], rq[4];
  if ((tid & 63) == 0) { rs[tid >> 6] = s; rq[tid >> 6] = qq; }
  __syncthreads();
  if (tid == 0) {
    s = rs[0] + rs[1] + rs[2] + rs[3];
    qq = rq[0] + rq[1] + rq[2] + rq[3];
    float mean = s * invN;
    float var = qq * invN - mean * mean;
    statout[j] = mean;
    statout[nj + j] = rsqrtf(var + 1e-8f);
  }
}

// ---------------- K2: h = dice1(z1); z2 = h @ W2 + b2; stats2 partials. thread = 1 row.
__global__ __launch_bounds__(256) void k_gemm2(
    const float* __restrict__ z1, const float* __restrict__ W2g,
    const float* __restrict__ b2, const float* __restrict__ alpha1,
    const float* __restrict__ stat1, float* __restrict__ z2,
    float* __restrict__ part2) {
  __shared__ float W2l[64 * 16];
  __shared__ float cf[208];        // mean[64], rstd[64], alpha[64], b2[16]
  __shared__ float red[256 * 33];  // per-thread 16 sums + 16 sqs, stride 33
  const int tid = threadIdx.x;
  if (tid < 64) {
    cf[tid] = stat1[tid];
    cf[64 + tid] = stat1[64 + tid];
    cf[128 + tid] = alpha1[tid];
  }
  if (tid < 16) cf[192 + tid] = b2[tid];
#pragma unroll
  for (int i = 0; i < 4; i++) { int idx = tid + 256 * i; W2l[idx] = W2g[idx]; }
  __syncthreads();
  const size_t row = (size_t)blockIdx.x * 256 + tid;
  const float* zr = z1 + row * 64;
  float acc[16];
#pragma unroll
  for (int j = 0; j < 16; j++) acc[j] = cf[192 + j];
  for (int k0 = 0; k0 < 64; k0 += 4) {
    f4 x4 = *(const f4*)(zr + k0);
#pragma unroll
    for (int dk = 0; dk < 4; dk++) {
      int k = k0 + dk;
      float x = x4[dk];
      float xn = (x - cf[k]) * cf[64 + k];
      float p = 1.f / (1.f + __expf(-xn));
      float h = x * (p + (1.f - p) * cf[128 + k]);
#pragma unroll
      for (int jc = 0; jc < 4; jc++) {
        f4 w = *(const f4*)(W2l + k * 16 + 4 * jc);
#pragma unroll
        for (int jj = 0; jj < 4; jj++) acc[4 * jc + jj] += h * w[jj];
      }
    }
  }
#pragma unroll
  for (int jc = 0; jc < 4; jc++) {
    f4 o;
#pragma unroll
    for (int jj = 0; jj < 4; jj++) o[jj] = acc[4 * jc + jj];
    *(f4*)(z2 + row * 16 + 4 * jc) = o;
  }
#pragma unroll
  for (int j = 0; j < 16; j++) {
    red[tid * 33 + j] = acc[j];
    red[tid * 33 + 16 + j] = acc[j] * acc[j];
  }
  __syncthreads();
  if (tid < 32) {   // cols 0..15 sums, 16..31 sqs; (g+tid)%32 conflict-free
    float s = 0.f;
    for (int g = 0; g < 256; g++) s += red[g * 33 + tid];
    part2[(size_t)tid * NB1 + blockIdx.x] = s;
  }
}

// ---------------- K3: dice2 -> inverted-mask softmax over T -> out = score @ hist
__global__ __launch_bounds__(256) void k_attn(
    const float* __restrict__ hist, const float* __restrict__ z2,
    const int* __restrict__ lens, const float* __restrict__ alpha2,
    const float* __restrict__ stat2, float* __restrict__ out) {
  __shared__ float lm[200 * 17];   // masked logits [t][h], +1 pad breaks stride-16
  __shared__ float sc[16 * 200];   // scores [h][t]
  const int tid = threadIdx.x;
  const int b = blockIdx.x;
  const int L = lens[b];
  {
    const int j = tid & 15, tb = tid >> 4;
    const float mu = stat2[j], rs = stat2[16 + j], al = alpha2[j];
    const float* z2b = z2 + (size_t)b * 3200;
#pragma unroll
    for (int i = 0; i < 13; i++) {
      int t = tb + 16 * i;
      if (t < 200) {
        float x = z2b[t * 16 + j];
        float xn = (x - mu) * rs;
        float p = 1.f / (1.f + __expf(-xn));
        float lg = x * (p + (1.f - p) * al);
        lm[t * 17 + j] = (t < L) ? 1e-9f : lg;   // reference: where(t<len, 1e-9, logits)
      }
    }
  }
  __syncthreads();
  {
    const int h = tid >> 4, s = tid & 15;        // 16-lane team per head column
    float v[13];
    float m = -1e30f;
#pragma unroll
    for (int i = 0; i < 13; i++) {
      int t = s + 16 * i;
      float x = (t < 200) ? lm[t * 17 + h] : -1e30f;
      v[i] = x;
      m = fmaxf(m, x);
    }
#pragma unroll
    for (int mk = 8; mk > 0; mk >>= 1) m = fmaxf(m, __shfl_xor(m, mk, 16));
    float sum = 0.f;
#pragma unroll
    for (int i = 0; i < 13; i++) {
      int t = s + 16 * i;
      if (t < 200) { float e = __expf(v[i] - m); v[i] = e; sum += e; }
    }
#pragma unroll
    for (int mk = 8; mk > 0; mk >>= 1) sum += __shfl_xor(sum, mk, 16);
    const float inv = 1.f / sum;
#pragma unroll
    for (int i = 0; i < 13; i++) {
      int t = s + 16 * i;
      if (t < 200) sc[h * 200 + t] = v[i] * inv;
    }
  }
  __syncthreads();
  {
    const int h = tid >> 4, e0 = (tid & 15) * 4;
    const float* hb = hist + (size_t)b * 200 * 64 + e0;
    const float* sh = sc + h * 200;
    f4 acc = 0.f;
    for (int t = 0; t < 200; t += 4) {
      f4 h0 = *(const f4*)(hb + (size_t)t * 64);
      f4 h1 = *(const f4*)(hb + (size_t)(t + 1) * 64);
      f4 h2 = *(const f4*)(hb + (size_t)(t + 2) * 64);
      f4 h3 = *(const f4*)(hb + (size_t)(t + 3) * 64);
      acc += h0 * sh[t];
      acc += h1 * sh[t + 1];
      acc += h2 * sh[t + 2];
      acc += h3 * sh[t + 3];
    }
    // out[b][h][e]: h*64+e0 == 4*tid -> fully coalesced
    *(f4*)(out + (size_t)b * 1024 + tid * 4) = acc;
  }
}

extern "C" void kernel_launch(void* const* d_in, const int* in_sizes, int n_in,
                              void* d_out, int out_size, void* d_ws, size_t ws_size,
                              hipStream_t stream) {
  const float* q    = (const float*)d_in[0];
  const float* hist = (const float*)d_in[1];
  const int*   len  = (const int*)d_in[2];
  const float* W1   = (const float*)d_in[3];
  const float* b1   = (const float*)d_in[4];
  const float* al1  = (const float*)d_in[5];
  const float* W2   = (const float*)d_in[6];
  const float* b2   = (const float*)d_in[7];
  const float* al2  = (const float*)d_in[8];
  float* out = (float*)d_out;

  // ws layout (floats): z1 | z2 | qW | part1[128][NB1] | part2[32][NB1] | stat1[128] | stat2[32]
  float* ws    = (float*)d_ws;
  float* z1    = ws;                               // 26,214,400
  float* z2    = z1 + (size_t)BT_ * 64;            //  6,553,600
  float* qW    = z2 + (size_t)BT_ * 16;            //    131,072
  float* part1 = qW + (size_t)B_ * 64;             //    204,800
  float* part2 = part1 + (size_t)128 * NB1;        //     51,200
  float* stat1 = part2 + (size_t)32 * NB1;         //        128
  float* stat2 = stat1 + 128;                      //         32
  (void)ws_size; (void)in_sizes; (void)n_in; (void)out_size;

  k_qw<<<dim3(128), dim3(256), 0, stream>>>(q, W1, b1, qW);
  k_gemm1<<<dim3(NB1), dim3(256), 0, stream>>>(q, hist, W1, qW, z1, part1);
  k_finalize<<<dim3(64), dim3(256), 0, stream>>>(part1, stat1, 64, NB1, 1.f / (float)BT_);
  k_gemm2<<<dim3(NB1), dim3(256), 0, stream>>>(z1, W2, b2, al1, stat1, z2, part2);
  k_finalize<<<dim3(16), dim3(256), 0, stream>>>(part2, stat2, 16, NB1, 1.f / (float)BT_);
  k_attn<<<dim3(B_), dim3(256), 0, stream>>>(hist, z2, len, al2, stat2, out);
}

// Round 2
// 543.353 us; speedup vs baseline: 2.9017x; 2.9017x over previous
//
#include <hip/hip_runtime.h>
#include <math.h>

// AttentionSequencePoolingLayer (DIN): fp32, multi-kernel.
// z1 = [q,h,q-h,q*h] @ W1 + b1  ==  qW(b) + h@(Wb-Wc) + (q*h)@Wd, qW = b1 + q@(Wa+Wc)
// dice needs global per-feature mean/var over (B,T) -> partials + finalize kernels.
// K3: inverted mask (t<len -> 1e-9), softmax over T, out = score @ hist.
//
// R1 -> R2: k_gemm1 showed 4.38 GB HBM traffic (27x write amplification) and
// VGPR_Count=84 (~512/6: allocator ignored the (256,3) hint and likely spilled).
// Fixes: (a) launch_bounds(256,2) + leaner inner loop (per-dk W loads, c-loop
// NOT unrolled), (b) microtile col remap {4tx, 32+4tx} so every z1 store instr
// is 128B-contiguous per 8-lane group, (c) part1/part2 transposed to
// [block][feature] (contiguous 512B per block instead of 4B x 128 lines).

typedef float f4 __attribute__((ext_vector_type(4)));

#define B_   2048
#define T_   200
#define BT_  409600        // B_*T_
#define NB1  1600          // blocks in K1/K2 (256 rows each)

// ---------------- qW precompute: qW[b][j] = b1[j] + sum_k q[b][k]*(W1[k][j]+W1[128+k][j])
__global__ __launch_bounds__(256) void k_qw(
    const float* __restrict__ q, const float* __restrict__ W1,
    const float* __restrict__ b1, float* __restrict__ qW) {
  __shared__ float Wac[64 * 65];   // +1 pad
  __shared__ float ql[16 * 64];
  const int tid = threadIdx.x;
#pragma unroll
  for (int i = 0; i < 16; i++) {
    int idx = tid + 256 * i;
    int k = idx >> 6, j = idx & 63;
    Wac[k * 65 + j] = W1[k * 64 + j] + W1[(128 + k) * 64 + j];
  }
  const int b0 = blockIdx.x * 16;
#pragma unroll
  for (int i = 0; i < 4; i++) {
    int idx = tid + 256 * i;
    ql[idx] = q[(size_t)b0 * 64 + idx];
  }
  __syncthreads();
  const int wv = tid >> 6, lane = tid & 63;
#pragma unroll
  for (int ii = 0; ii < 4; ii++) {
    const int bl = wv * 4 + ii;
    float acc = b1[lane];
#pragma unroll 8
    for (int k = 0; k < 64; k++) acc += ql[bl * 64 + k] * Wac[k * 65 + lane];
    qW[(size_t)(b0 + bl) * 64 + lane] = acc;
  }
}

// ---------------- K1: z1[BT][64] = A[BT][128] @ Wcomb[128][64] + qW(b); stats1 partials
// A cols 0..63 = h, 64..127 = q*h ; Wcomb rows 0..63 = Wb-Wc, 64..127 = Wd
// Thread (wv,ty,tx): rows rbase+8i (rbase=64wv+ty), cols {4tx..4tx+3, 32+4tx..32+4tx+3}
__global__ __launch_bounds__(256, 2) void k_gemm1(
    const float* __restrict__ q, const float* __restrict__ hist,
    const float* __restrict__ W1, const float* __restrict__ qW,
    float* __restrict__ z1, float* __restrict__ part1) {
  __shared__ float As[256 * 36];   // [row][kk] stride 36: 16B-aligned rows
  __shared__ float Wl[32 * 64];    // W chunk [kk][j]
  const int tid = threadIdx.x;
  const int R0 = blockIdx.x * 256;
  const int wv = tid >> 6, ty = (tid >> 3) & 7, tx = tid & 7;
  const int c0 = 4 * tx;
  const int rbase = 64 * wv + ty;

  float acc[8][8];
#pragma unroll
  for (int i = 0; i < 8; i++) {
    int R = R0 + rbase + 8 * i;
    int b = (int)((unsigned)R / 200u);
    f4 qa = *(const f4*)(qW + (size_t)b * 64 + c0);
    f4 qb = *(const f4*)(qW + (size_t)b * 64 + 32 + c0);
#pragma unroll
    for (int jj = 0; jj < 4; jj++) { acc[i][jj] = qa[jj]; acc[i][4 + jj] = qb[jj]; }
  }

#pragma unroll 1
  for (int c = 0; c < 4; c++) {
    const int kb = (c & 1) * 32;   // source col base in hist/q
    const int kw = c * 32;         // combined-W row base
    __syncthreads();
    // stage W chunk (2048 floats)
#pragma unroll
    for (int i = 0; i < 8; i++) {
      int idx = tid + 256 * i;
      int k = idx >> 6, j = idx & 63;
      int kg = kw + k;
      float w;
      if (kg < 64) w = W1[(64 + kg) * 64 + j] - W1[(128 + kg) * 64 + j];
      else         w = W1[(128 + kg) * 64 + j];
      Wl[idx] = w;
    }
    // stage A chunk: 2048 f4 pieces (8 rows x 128B contiguous per wave instr)
#pragma unroll
    for (int i = 0; i < 8; i++) {
      int p = tid + 256 * i;
      int row = p >> 3, k4 = p & 7;
      int R = R0 + row;
      f4 h4 = *(const f4*)(hist + (size_t)R * 64 + kb + 4 * k4);
      if (c >= 2) {
        int b = (int)((unsigned)R / 200u);
        f4 q4 = *(const f4*)(q + (size_t)b * 64 + kb + 4 * k4);
        h4 *= q4;
      }
      *(f4*)(As + row * 36 + 4 * k4) = h4;
    }
    __syncthreads();
#pragma unroll
    for (int k0 = 0; k0 < 32; k0 += 4) {
      f4 a[8];
#pragma unroll
      for (int i = 0; i < 8; i++)
        a[i] = *(const f4*)(As + (rbase + 8 * i) * 36 + k0);
#pragma unroll
      for (int dk = 0; dk < 4; dk++) {
        f4 w0 = *(const f4*)(Wl + (k0 + dk) * 64 + c0);
        f4 w1 = *(const f4*)(Wl + (k0 + dk) * 64 + 32 + c0);
#pragma unroll
        for (int i = 0; i < 8; i++) {
          float av = a[i][dk];
#pragma unroll
          for (int jj = 0; jj < 4; jj++) {
            acc[i][jj]     += av * w0[jj];
            acc[i][4 + jj] += av * w1[jj];
          }
        }
      }
    }
  }

  // store z1: two 128B-contiguous store groups per (ty, i)
#pragma unroll
  for (int i = 0; i < 8; i++) {
    int R = R0 + rbase + 8 * i;
    f4 o0, o1;
#pragma unroll
    for (int jj = 0; jj < 4; jj++) { o0[jj] = acc[i][jj]; o1[jj] = acc[i][4 + jj]; }
    *(f4*)(z1 + (size_t)R * 64 + c0) = o0;
    *(f4*)(z1 + (size_t)R * 64 + 32 + c0) = o1;
  }

  // per-block stats (sum, sumsq per feature over the 256 rows)
  float s8[8], q8[8];
#pragma unroll
  for (int jj = 0; jj < 8; jj++) { s8[jj] = 0.f; q8[jj] = 0.f; }
#pragma unroll
  for (int i = 0; i < 8; i++)
#pragma unroll
    for (int jj = 0; jj < 8; jj++) { float v = acc[i][jj]; s8[jj] += v; q8[jj] += v * v; }
  __syncthreads();
  float* red = As;   // reuse: [32][64] sums + [32][64] sqs = 16KB
  const int g = tid >> 3;
#pragma unroll
  for (int jj = 0; jj < 4; jj++) {
    red[g * 64 + c0 + jj] = s8[jj];
    red[g * 64 + 32 + c0 + jj] = s8[4 + jj];
    red[2048 + g * 64 + c0 + jj] = q8[jj];
    red[2048 + g * 64 + 32 + c0 + jj] = q8[4 + jj];
  }
  __syncthreads();
  if (tid < 64) {
    float s = 0.f, qq = 0.f;
    for (int gg = 0; gg < 32; gg++) { s += red[gg * 64 + tid]; qq += red[2048 + gg * 64 + tid]; }
    part1[(size_t)blockIdx.x * 128 + tid] = s;        // [block][feature]: contiguous
    part1[(size_t)blockIdx.x * 128 + 64 + tid] = qq;
  }
}

// ---------------- finalize: mean/rstd per feature from [block][feature] partials
__global__ __launch_bounds__(256) void k_finalize(
    const float* __restrict__ part, float* __restrict__ statout,
    int nj, int stride, int nb, float invN) {
  const int j = blockIdx.x, tid = threadIdx.x;
  float s = 0.f, qq = 0.f;
  for (int i = tid; i < nb; i += 256) {
    s += part[(size_t)i * stride + j];
    qq += part[(size_t)i * stride + nj + j];
  }
#pragma unroll
  for (int off = 32; off > 0; off >>= 1) {
    s += __shfl_down(s, off);
    qq += __shfl_down(qq, off);
  }
  __shared__ float rs[4], rq[4];
  if ((tid & 63) == 0) { rs[tid >> 6] = s; rq[tid >> 6] = qq; }
  __syncthreads();
  if (tid == 0) {
    s = rs[0] + rs[1] + rs[2] + rs[3];
    qq = rq[0] + rq[1] + rq[2] + rq[3];
    float mean = s * invN;
    float var = qq * invN - mean * mean;
    statout[j] = mean;
    statout[nj + j] = rsqrtf(var + 1e-8f);
  }
}

// ---------------- K2: h = dice1(z1); z2 = h @ W2 + b2; stats2 partials. thread = 1 row.
__global__ __launch_bounds__(256) void k_gemm2(
    const float* __restrict__ z1, const float* __restrict__ W2g,
    const float* __restrict__ b2, const float* __restrict__ alpha1,
    const float* __restrict__ stat1, float* __restrict__ z2,
    float* __restrict__ part2) {
  __shared__ float W2l[64 * 16];
  __shared__ float cf[208];        // mean[64], rstd[64], alpha[64], b2[16]
  __shared__ float red[256 * 33];  // per-thread 16 sums + 16 sqs, stride 33
  const int tid = threadIdx.x;
  if (tid < 64) {
    cf[tid] = stat1[tid];
    cf[64 + tid] = stat1[64 + tid];
    cf[128 + tid] = alpha1[tid];
  }
  if (tid < 16) cf[192 + tid] = b2[tid];
#pragma unroll
  for (int i = 0; i < 4; i++) { int idx = tid + 256 * i; W2l[idx] = W2g[idx]; }
  __syncthreads();
  const size_t row = (size_t)blockIdx.x * 256 + tid;
  const float* zr = z1 + row * 64;
  float acc[16];
#pragma unroll
  for (int j = 0; j < 16; j++) acc[j] = cf[192 + j];
  for (int k0 = 0; k0 < 64; k0 += 4) {
    f4 x4 = *(const f4*)(zr + k0);
#pragma unroll
    for (int dk = 0; dk < 4; dk++) {
      int k = k0 + dk;
      float x = x4[dk];
      float xn = (x - cf[k]) * cf[64 + k];
      float p = 1.f / (1.f + __expf(-xn));
      float h = x * (p + (1.f - p) * cf[128 + k]);
#pragma unroll
      for (int jc = 0; jc < 4; jc++) {
        f4 w = *(const f4*)(W2l + k * 16 + 4 * jc);
#pragma unroll
        for (int jj = 0; jj < 4; jj++) acc[4 * jc + jj] += h * w[jj];
      }
    }
  }
#pragma unroll
  for (int jc = 0; jc < 4; jc++) {
    f4 o;
#pragma unroll
    for (int jj = 0; jj < 4; jj++) o[jj] = acc[4 * jc + jj];
    *(f4*)(z2 + row * 16 + 4 * jc) = o;
  }
#pragma unroll
  for (int j = 0; j < 16; j++) {
    red[tid * 33 + j] = acc[j];
    red[tid * 33 + 16 + j] = acc[j] * acc[j];
  }
  __syncthreads();
  if (tid < 32) {
    float s = 0.f;
    for (int g = 0; g < 256; g++) s += red[g * 33 + tid];
    part2[(size_t)blockIdx.x * 32 + tid] = s;   // [block][feature]: contiguous
  }
}

// ---------------- K3: dice2 -> inverted-mask softmax over T -> out = score @ hist
__global__ __launch_bounds__(256) void k_attn(
    const float* __restrict__ hist, const float* __restrict__ z2,
    const int* __restrict__ lens, const float* __restrict__ alpha2,
    const float* __restrict__ stat2, float* __restrict__ out) {
  __shared__ float lm[200 * 17];   // masked logits [t][h], +1 pad
  __shared__ float sc[16 * 200];   // scores [h][t]
  const int tid = threadIdx.x;
  const int b = blockIdx.x;
  const int L = lens[b];
  {
    const int j = tid & 15, tb = tid >> 4;
    const float mu = stat2[j], rs = stat2[16 + j], al = alpha2[j];
    const float* z2b = z2 + (size_t)b * 3200;
#pragma unroll
    for (int i = 0; i < 13; i++) {
      int t = tb + 16 * i;
      if (t < 200) {
        float x = z2b[t * 16 + j];
        float xn = (x - mu) * rs;
        float p = 1.f / (1.f + __expf(-xn));
        float lg = x * (p + (1.f - p) * al);
        lm[t * 17 + j] = (t < L) ? 1e-9f : lg;   // reference: where(t<len, 1e-9, logits)
      }
    }
  }
  __syncthreads();
  {
    const int h = tid >> 4, s = tid & 15;        // 16-lane team per head
    float v[13];
    float m = -1e30f;
#pragma unroll
    for (int i = 0; i < 13; i++) {
      int t = s + 16 * i;
      float x = (t < 200) ? lm[t * 17 + h] : -1e30f;
      v[i] = x;
      m = fmaxf(m, x);
    }
#pragma unroll
    for (int mk = 8; mk > 0; mk >>= 1) m = fmaxf(m, __shfl_xor(m, mk, 16));
    float sum = 0.f;
#pragma unroll
    for (int i = 0; i < 13; i++) {
      int t = s + 16 * i;
      if (t < 200) { float e = __expf(v[i] - m); v[i] = e; sum += e; }
    }
#pragma unroll
    for (int mk = 8; mk > 0; mk >>= 1) sum += __shfl_xor(sum, mk, 16);
    const float inv = 1.f / sum;
#pragma unroll
    for (int i = 0; i < 13; i++) {
      int t = s + 16 * i;
      if (t < 200) sc[h * 200 + t] = v[i] * inv;
    }
  }
  __syncthreads();
  {
    const int h = tid >> 4, e0 = (tid & 15) * 4;
    const float* hb = hist + (size_t)b * 200 * 64 + e0;
    const float* sh = sc + h * 200;
    f4 acc = 0.f;
    for (int t = 0; t < 200; t += 4) {
      f4 h0 = *(const f4*)(hb + (size_t)t * 64);
      f4 h1 = *(const f4*)(hb + (size_t)(t + 1) * 64);
      f4 h2 = *(const f4*)(hb + (size_t)(t + 2) * 64);
      f4 h3 = *(const f4*)(hb + (size_t)(t + 3) * 64);
      acc += h0 * sh[t];
      acc += h1 * sh[t + 1];
      acc += h2 * sh[t + 2];
      acc += h3 * sh[t + 3];
    }
    *(f4*)(out + (size_t)b * 1024 + tid * 4) = acc;   // 4*tid: fully coalesced
  }
}

extern "C" void kernel_launch(void* const* d_in, const int* in_sizes, int n_in,
                              void* d_out, int out_size, void* d_ws, size_t ws_size,
                              hipStream_t stream) {
  const float* q    = (const float*)d_in[0];
  const float* hist = (const float*)d_in[1];
  const int*   len  = (const int*)d_in[2];
  const float* W1   = (const float*)d_in[3];
  const float* b1   = (const float*)d_in[4];
  const float* al1  = (const float*)d_in[5];
  const float* W2   = (const float*)d_in[6];
  const float* b2   = (const float*)d_in[7];
  const float* al2  = (const float*)d_in[8];
  float* out = (float*)d_out;

  // ws layout (floats): z1 | z2 | qW | part1[NB1][128] | part2[NB1][32] | stat1[128] | stat2[32]
  float* ws    = (float*)d_ws;
  float* z1    = ws;                               // 26,214,400
  float* z2    = z1 + (size_t)BT_ * 64;            //  6,553,600
  float* qW    = z2 + (size_t)BT_ * 16;            //    131,072
  float* part1 = qW + (size_t)B_ * 64;             //    204,800
  float* part2 = part1 + (size_t)NB1 * 128;        //     51,200
  float* stat1 = part2 + (size_t)NB1 * 32;         //        128
  float* stat2 = stat1 + 128;                      //         32
  (void)ws_size; (void)in_sizes; (void)n_in; (void)out_size;

  k_qw<<<dim3(128), dim3(256), 0, stream>>>(q, W1, b1, qW);
  k_gemm1<<<dim3(NB1), dim3(256), 0, stream>>>(q, hist, W1, qW, z1, part1);
  k_finalize<<<dim3(64), dim3(256), 0, stream>>>(part1, stat1, 64, 128, NB1, 1.f / (float)BT_);
  k_gemm2<<<dim3(NB1), dim3(256), 0, stream>>>(z1, W2, b2, al1, stat1, z2, part2);
  k_finalize<<<dim3(16), dim3(256), 0, stream>>>(part2, stat2, 16, 32, NB1, 1.f / (float)BT_);
  k_attn<<<dim3(B_), dim3(256), 0, stream>>>(hist, z2, len, al2, stat2, out);
}

// Round 3
// 282.657 us; speedup vs baseline: 5.5779x; 1.9223x over previous
//
#include <hip/hip_runtime.h>
#include <math.h>

// AttentionSequencePoolingLayer (DIN), R3: bf16-MFMA GEMM1.
// z1 = [q,h,q-h,q*h] @ W1 + b1  ==  qW(b) + [h | q*h] @ Wcomb,
//   qW = b1 + q@(Wa+Wc), Wcomb = [Wb-Wc ; Wd]  (K=128, N=64)
// R2 showed k_gemm1 latency-bound fp32 VALU (22% HBM, 18% VALU, MfmaUtil 0),
// with 2x hist re-read and 2.5x write amplification. R3: MFMA 16x16x32_bf16,
// single hist read per tile, z1 stored bf16 via LDS repack (full-line stores).

typedef float f4 __attribute__((ext_vector_type(4)));
typedef float f32x4 __attribute__((ext_vector_type(4)));
typedef short s8v __attribute__((ext_vector_type(8)));
typedef short s4v __attribute__((ext_vector_type(4)));
typedef unsigned short u16;

#define B_   2048
#define T_   200
#define BT_  409600        // B_*T_
#define NB1  3200          // k_gemm1 blocks (128 rows each)
#define NB2  1600          // k_gemm2 blocks (256 rows each)

static __device__ __forceinline__ u16 f2bf(float f) {
  union { float f; unsigned u; } v; v.f = f;
  unsigned r = v.u + 0x7fffu + ((v.u >> 16) & 1u);   // RNE
  return (u16)(r >> 16);
}
static __device__ __forceinline__ float bf2f(u16 s) {
  union { unsigned u; float f; } v; v.u = ((unsigned)s) << 16;
  return v.f;
}

// ---------------- qW precompute: qW[b][j] = b1[j] + sum_k q[b][k]*(W1[k][j]+W1[128+k][j])
__global__ __launch_bounds__(256) void k_qw(
    const float* __restrict__ q, const float* __restrict__ W1,
    const float* __restrict__ b1, float* __restrict__ qW) {
  __shared__ float Wac[64 * 65];
  __shared__ float ql[16 * 64];
  const int tid = threadIdx.x;
#pragma unroll
  for (int i = 0; i < 16; i++) {
    int idx = tid + 256 * i;
    int k = idx >> 6, j = idx & 63;
    Wac[k * 65 + j] = W1[k * 64 + j] + W1[(128 + k) * 64 + j];
  }
  const int b0 = blockIdx.x * 16;
#pragma unroll
  for (int i = 0; i < 4; i++) {
    int idx = tid + 256 * i;
    ql[idx] = q[(size_t)b0 * 64 + idx];
  }
  __syncthreads();
  const int wv = tid >> 6, lane = tid & 63;
#pragma unroll
  for (int ii = 0; ii < 4; ii++) {
    const int bl = wv * 4 + ii;
    float acc = b1[lane];
#pragma unroll 8
    for (int k = 0; k < 64; k++) acc += ql[bl * 64 + k] * Wac[k * 65 + lane];
    qW[(size_t)(b0 + bl) * 64 + lane] = acc;
  }
}

// ---------------- W prep: wsWT[n][k] = Wcomb[k][n] in bf16  (64 x 128)
__global__ __launch_bounds__(256) void k_wprep(
    const float* __restrict__ W1, u16* __restrict__ wsWT) {
  int t = threadIdx.x + blockIdx.x * 256;   // 8192 total
  int n = t >> 7, k = t & 127;
  float w = (k < 64) ? (W1[(64 + k) * 64 + n] - W1[(128 + k) * 64 + n])
                     : W1[(128 + k) * 64 + n];
  wsWT[t] = f2bf(w);
}

// ---------------- K1: z1[BT][64](bf16) = [h | q*h](bf16) @ Wcomb(bf16) + qW; stats1
// 128-row tile, 4 waves; wave wv: rows 32wv..32wv+31 (2 m-tiles), all 4 n-tiles.
__global__ __launch_bounds__(256, 3) void k_gemm1(
    const float* __restrict__ q, const float* __restrict__ hist,
    const u16* __restrict__ wsWT, const float* __restrict__ qW,
    u16* __restrict__ z1, float* __restrict__ part1) {
  __shared__ __align__(16) u16 As[128 * 136];   // A tile [m][k], k-stride 136 (pad: 2-way max)
  __shared__ __align__(16) u16 Ws[64 * 136];    // W^T [n][k]
  const int tid = threadIdx.x;
  const int R0 = blockIdx.x * 128;

  // stage W^T (16 KB) from wsWT [64][128]
#pragma unroll
  for (int i = 0; i < 4; i++) {
    int piece = tid + 256 * i;               // 0..1023 pieces of 8 bf16
    int n = piece >> 4, k8 = piece & 15;
    *(s8v*)(Ws + n * 136 + 8 * k8) = *(const s8v*)(wsWT + n * 128 + 8 * k8);
  }
  // stage A: single hist read; cols 0..63 = h, 64..127 = q*h
#pragma unroll
  for (int i = 0; i < 8; i++) {
    int piece = tid + 256 * i;               // 0..2047 pieces of 4 floats
    int row = piece >> 4, c4 = piece & 15;
    int R = R0 + row;
    int b = (int)((unsigned)R / 200u);
    f4 h4 = *(const f4*)(hist + (size_t)R * 64 + 4 * c4);
    f4 q4 = *(const f4*)(q + (size_t)b * 64 + 4 * c4);
    f4 p4 = h4 * q4;
    s4v hv, pv;
#pragma unroll
    for (int j = 0; j < 4; j++) { hv[j] = (short)f2bf(h4[j]); pv[j] = (short)f2bf(p4[j]); }
    *(s4v*)(As + row * 136 + 4 * c4) = hv;
    *(s4v*)(As + row * 136 + 64 + 4 * c4) = pv;
  }
  __syncthreads();

  const int wv = tid >> 6, lane = tid & 63;
  const int lm = lane & 15, quad = lane >> 4;
  f32x4 acc[2][4];
#pragma unroll
  for (int mt = 0; mt < 2; mt++)
#pragma unroll
    for (int nt = 0; nt < 4; nt++) acc[mt][nt] = (f32x4)0.f;

#pragma unroll
  for (int c = 0; c < 4; c++) {
    const int ko = 32 * c + 8 * quad;
    s8v a0 = *(const s8v*)(As + (32 * wv + lm) * 136 + ko);
    s8v a1 = *(const s8v*)(As + (32 * wv + 16 + lm) * 136 + ko);
#pragma unroll
    for (int nt = 0; nt < 4; nt++) {
      s8v b8 = *(const s8v*)(Ws + (16 * nt + lm) * 136 + ko);
      acc[0][nt] = __builtin_amdgcn_mfma_f32_16x16x32_bf16(a0, b8, acc[0][nt], 0, 0, 0);
      acc[1][nt] = __builtin_amdgcn_mfma_f32_16x16x32_bf16(a1, b8, acc[1][nt], 0, 0, 0);
    }
  }
  __syncthreads();   // done with As/Ws as staged; reuse below

  // epilogue: add qW bias, per-lane stats, bf16 repack via LDS
  u16* zs = As;                 // [128][72] bf16
  float* red = (float*)Ws;      // red_s[16][64] | red_q[16][64]
  const int g = wv * 4 + quad;  // 16 groups of 16 lanes
  float s[4] = {0.f, 0.f, 0.f, 0.f}, sq[4] = {0.f, 0.f, 0.f, 0.f};
#pragma unroll
  for (int mt = 0; mt < 2; mt++)
#pragma unroll
    for (int nt = 0; nt < 4; nt++)
#pragma unroll
      for (int r = 0; r < 4; r++) {
        int row = 32 * wv + 16 * mt + 4 * quad + r;   // C-layout: row=(lane>>4)*4+reg
        int R = R0 + row;
        int b = (int)((unsigned)R / 200u);
        int col = 16 * nt + lm;                        // C-layout: col=lane&15
        float v = acc[mt][nt][r] + qW[(size_t)b * 64 + col];
        s[nt] += v; sq[nt] += v * v;
        zs[row * 72 + col] = f2bf(v);
      }
#pragma unroll
  for (int nt = 0; nt < 4; nt++) {
    red[g * 64 + 16 * nt + lm] = s[nt];
    red[1024 + g * 64 + 16 * nt + lm] = sq[nt];
  }
  __syncthreads();
  // coalesced z1 store: 128 rows x 128 B
#pragma unroll
  for (int i = 0; i < 4; i++) {
    int piece = tid + 256 * i;               // 0..1023 pieces of 8 bf16
    int row = piece >> 3, seg = piece & 7;
    s8v v = *(const s8v*)(zs + row * 72 + 8 * seg);
    *(s8v*)(z1 + (size_t)(R0 + row) * 64 + 8 * seg) = v;
  }
  if (tid < 64) {
    float ss = 0.f, qq = 0.f;
#pragma unroll
    for (int gg = 0; gg < 16; gg++) { ss += red[gg * 64 + tid]; qq += red[1024 + gg * 64 + tid]; }
    part1[(size_t)blockIdx.x * 128 + tid] = ss;
    part1[(size_t)blockIdx.x * 128 + 64 + tid] = qq;
  }
}

// ---------------- finalize: mean/rstd per feature from [block][feature] partials
__global__ __launch_bounds__(256) void k_finalize(
    const float* __restrict__ part, float* __restrict__ statout,
    int nj, int stride, int nb, float invN) {
  const int j = blockIdx.x, tid = threadIdx.x;
  float s = 0.f, qq = 0.f;
  for (int i = tid; i < nb; i += 256) {
    s += part[(size_t)i * stride + j];
    qq += part[(size_t)i * stride + nj + j];
  }
#pragma unroll
  for (int off = 32; off > 0; off >>= 1) {
    s += __shfl_down(s, off);
    qq += __shfl_down(qq, off);
  }
  __shared__ float rs[4], rq[4];
  if ((tid & 63) == 0) { rs[tid >> 6] = s; rq[tid >> 6] = qq; }
  __syncthreads();
  if (tid == 0) {
    s = rs[0] + rs[1] + rs[2] + rs[3];
    qq = rq[0] + rq[1] + rq[2] + rq[3];
    float mean = s * invN;
    float var = qq * invN - mean * mean;
    statout[j] = mean;
    statout[nj + j] = rsqrtf(var + 1e-8f);
  }
}

// ---------------- K2: h = dice1(z1 bf16); z2 = h @ W2 + b2; stats2. thread = 1 row.
__global__ __launch_bounds__(256) void k_gemm2(
    const u16* __restrict__ z1, const float* __restrict__ W2g,
    const float* __restrict__ b2, const float* __restrict__ alpha1,
    const float* __restrict__ stat1, float* __restrict__ z2,
    float* __restrict__ part2) {
  __shared__ float W2l[64 * 16];
  __shared__ float cf[208];        // mean[64], rstd[64], alpha[64], b2[16]
  __shared__ float red[256 * 33];  // per-thread 16 sums + 16 sqs
  const int tid = threadIdx.x;
  if (tid < 64) {
    cf[tid] = stat1[tid];
    cf[64 + tid] = stat1[64 + tid];
    cf[128 + tid] = alpha1[tid];
  }
  if (tid < 16) cf[192 + tid] = b2[tid];
#pragma unroll
  for (int i = 0; i < 4; i++) { int idx = tid + 256 * i; W2l[idx] = W2g[idx]; }
  __syncthreads();
  const size_t row = (size_t)blockIdx.x * 256 + tid;
  const u16* zr = z1 + row * 64;
  float acc[16];
#pragma unroll
  for (int j = 0; j < 16; j++) acc[j] = cf[192 + j];
  for (int k0 = 0; k0 < 64; k0 += 8) {
    s8v x8 = *(const s8v*)(zr + k0);
#pragma unroll
    for (int dk = 0; dk < 8; dk++) {
      int k = k0 + dk;
      float x = bf2f((u16)x8[dk]);
      float xn = (x - cf[k]) * cf[64 + k];
      float p = 1.f / (1.f + __expf(-xn));
      float h = x * (p + (1.f - p) * cf[128 + k]);
#pragma unroll
      for (int jc = 0; jc < 4; jc++) {
        f4 w = *(const f4*)(W2l + k * 16 + 4 * jc);
#pragma unroll
        for (int jj = 0; jj < 4; jj++) acc[4 * jc + jj] += h * w[jj];
      }
    }
  }
#pragma unroll
  for (int jc = 0; jc < 4; jc++) {
    f4 o;
#pragma unroll
    for (int jj = 0; jj < 4; jj++) o[jj] = acc[4 * jc + jj];
    *(f4*)(z2 + row * 16 + 4 * jc) = o;
  }
#pragma unroll
  for (int j = 0; j < 16; j++) {
    red[tid * 33 + j] = acc[j];
    red[tid * 33 + 16 + j] = acc[j] * acc[j];
  }
  __syncthreads();
  if (tid < 32) {
    float s = 0.f;
    for (int g = 0; g < 256; g++) s += red[g * 33 + tid];
    part2[(size_t)blockIdx.x * 32 + tid] = s;
  }
}

// ---------------- K3: dice2 -> inverted-mask softmax over T -> out = score @ hist
__global__ __launch_bounds__(256) void k_attn(
    const float* __restrict__ hist, const float* __restrict__ z2,
    const int* __restrict__ lens, const float* __restrict__ alpha2,
    const float* __restrict__ stat2, float* __restrict__ out) {
  __shared__ float lm[200 * 17];
  __shared__ float sc[16 * 200];
  const int tid = threadIdx.x;
  const int b = blockIdx.x;
  const int L = lens[b];
  {
    const int j = tid & 15, tb = tid >> 4;
    const float mu = stat2[j], rs = stat2[16 + j], al = alpha2[j];
    const float* z2b = z2 + (size_t)b * 3200;
#pragma unroll
    for (int i = 0; i < 13; i++) {
      int t = tb + 16 * i;
      if (t < 200) {
        float x = z2b[t * 16 + j];
        float xn = (x - mu) * rs;
        float p = 1.f / (1.f + __expf(-xn));
        float lg = x * (p + (1.f - p) * al);
        lm[t * 17 + j] = (t < L) ? 1e-9f : lg;   // reference: where(t<len, 1e-9, logits)
      }
    }
  }
  __syncthreads();
  {
    const int h = tid >> 4, s = tid & 15;
    float v[13];
    float m = -1e30f;
#pragma unroll
    for (int i = 0; i < 13; i++) {
      int t = s + 16 * i;
      float x = (t < 200) ? lm[t * 17 + h] : -1e30f;
      v[i] = x;
      m = fmaxf(m, x);
    }
#pragma unroll
    for (int mk = 8; mk > 0; mk >>= 1) m = fmaxf(m, __shfl_xor(m, mk, 16));
    float sum = 0.f;
#pragma unroll
    for (int i = 0; i < 13; i++) {
      int t = s + 16 * i;
      if (t < 200) { float e = __expf(v[i] - m); v[i] = e; sum += e; }
    }
#pragma unroll
    for (int mk = 8; mk > 0; mk >>= 1) sum += __shfl_xor(sum, mk, 16);
    const float inv = 1.f / sum;
#pragma unroll
    for (int i = 0; i < 13; i++) {
      int t = s + 16 * i;
      if (t < 200) sc[h * 200 + t] = v[i] * inv;
    }
  }
  __syncthreads();
  {
    const int h = tid >> 4, e0 = (tid & 15) * 4;
    const float* hb = hist + (size_t)b * 200 * 64 + e0;
    const float* sh = sc + h * 200;
    f4 acc = 0.f;
    for (int t = 0; t < 200; t += 4) {
      f4 h0 = *(const f4*)(hb + (size_t)t * 64);
      f4 h1 = *(const f4*)(hb + (size_t)(t + 1) * 64);
      f4 h2 = *(const f4*)(hb + (size_t)(t + 2) * 64);
      f4 h3 = *(const f4*)(hb + (size_t)(t + 3) * 64);
      acc += h0 * sh[t];
      acc += h1 * sh[t + 1];
      acc += h2 * sh[t + 2];
      acc += h3 * sh[t + 3];
    }
    *(f4*)(out + (size_t)b * 1024 + tid * 4) = acc;
  }
}

extern "C" void kernel_launch(void* const* d_in, const int* in_sizes, int n_in,
                              void* d_out, int out_size, void* d_ws, size_t ws_size,
                              hipStream_t stream) {
  const float* q    = (const float*)d_in[0];
  const float* hist = (const float*)d_in[1];
  const int*   len  = (const int*)d_in[2];
  const float* W1   = (const float*)d_in[3];
  const float* b1   = (const float*)d_in[4];
  const float* al1  = (const float*)d_in[5];
  const float* W2   = (const float*)d_in[6];
  const float* b2   = (const float*)d_in[7];
  const float* al2  = (const float*)d_in[8];
  float* out = (float*)d_out;

  // ws layout (bytes): z1(bf16) | z2(f32) | qW | wsWT(bf16) | part1 | part2 | stat1 | stat2
  char* ws = (char*)d_ws;
  u16*   z1    = (u16*)ws;                                   // 52,428,800 B
  float* z2    = (float*)(ws + 52428800);                    // 26,214,400 B
  float* qW    = (float*)(ws + 52428800 + 26214400);         //    524,288 B
  u16*   wsWT  = (u16*)((char*)qW + 524288);                 //     16,384 B
  float* part1 = (float*)((char*)wsWT + 16384);              //  1,638,400 B
  float* part2 = part1 + (size_t)NB1 * 128;                  //    204,800 B
  float* stat1 = part2 + (size_t)NB2 * 32;                   //        512 B
  float* stat2 = stat1 + 128;                                //        128 B
  (void)ws_size; (void)in_sizes; (void)n_in; (void)out_size;

  k_qw<<<dim3(128), dim3(256), 0, stream>>>(q, W1, b1, qW);
  k_wprep<<<dim3(32), dim3(256), 0, stream>>>(W1, wsWT);
  k_gemm1<<<dim3(NB1), dim3(256), 0, stream>>>(q, hist, wsWT, qW, z1, part1);
  k_finalize<<<dim3(64), dim3(256), 0, stream>>>(part1, stat1, 64, 128, NB1, 1.f / (float)BT_);
  k_gemm2<<<dim3(NB2), dim3(256), 0, stream>>>(z1, W2, b2, al1, stat1, z2, part2);
  k_finalize<<<dim3(16), dim3(256), 0, stream>>>(part2, stat2, 16, 32, NB2, 1.f / (float)BT_);
  k_attn<<<dim3(B_), dim3(256), 0, stream>>>(hist, z2, len, al2, stat2, out);
}

// Round 5
// 255.571 us; speedup vs baseline: 6.1691x; 1.1060x over previous
//
#include <hip/hip_runtime.h>
#include <math.h>

// AttentionSequencePoolingLayer (DIN), R4b.
// R4 NaN root cause: hT K-pad clear only covered 192/256 chunks (tid<320 on a
// 256-thread block) -> uninitialized LDS entered MFMA as 0*Inf = NaN for
// e in [48,64). Fixed with a strided loop over all 320 pad chunks.
// Design otherwise identical to R4: MFMA score@hist in k_attn (hist staged once
// per block, transposed bf16), z2 bf16, parallel gemm2 tail, wprep in k_qw.

typedef float f4 __attribute__((ext_vector_type(4)));
typedef float f32x4 __attribute__((ext_vector_type(4)));
typedef short s8v __attribute__((ext_vector_type(8)));
typedef short s4v __attribute__((ext_vector_type(4)));
typedef unsigned short u16;

#define B_   2048
#define T_   200
#define BT_  409600        // B_*T_
#define NB1  3200          // k_gemm1 blocks (128 rows each)
#define NB2  1600          // k_gemm2 blocks (256 rows each)

static __device__ __forceinline__ u16 f2bf(float f) {
  union { float f; unsigned u; } v; v.f = f;
  unsigned r = v.u + 0x7fffu + ((v.u >> 16) & 1u);   // RNE
  return (u16)(r >> 16);
}
static __device__ __forceinline__ float bf2f(u16 s) {
  union { unsigned u; float f; } v; v.u = ((unsigned)s) << 16;
  return v.f;
}

// ---------------- qW precompute + (blocks<32) W-prep
// qW[b][j] = b1[j] + sum_k q[b][k]*(W1[k][j]+W1[128+k][j])
// wsWT[n][k] = Wcomb[k][n] bf16, Wcomb = [Wb-Wc ; Wd]
__global__ __launch_bounds__(256) void k_qw(
    const float* __restrict__ q, const float* __restrict__ W1,
    const float* __restrict__ b1, float* __restrict__ qW,
    u16* __restrict__ wsWT) {
  __shared__ float Wac[64 * 65];
  __shared__ float ql[16 * 64];
  const int tid = threadIdx.x;
#pragma unroll
  for (int i = 0; i < 16; i++) {
    int idx = tid + 256 * i;
    int k = idx >> 6, j = idx & 63;
    Wac[k * 65 + j] = W1[k * 64 + j] + W1[(128 + k) * 64 + j];
  }
  const int b0 = blockIdx.x * 16;
#pragma unroll
  for (int i = 0; i < 4; i++) {
    int idx = tid + 256 * i;
    ql[idx] = q[(size_t)b0 * 64 + idx];
  }
  __syncthreads();
  const int wv = tid >> 6, lane = tid & 63;
#pragma unroll
  for (int ii = 0; ii < 4; ii++) {
    const int bl = wv * 4 + ii;
    float acc = b1[lane];
#pragma unroll 8
    for (int k = 0; k < 64; k++) acc += ql[bl * 64 + k] * Wac[k * 65 + lane];
    qW[(size_t)(b0 + bl) * 64 + lane] = acc;
  }
  if (blockIdx.x < 32) {
    int t = blockIdx.x * 256 + tid;   // 8192 total
    int n = t >> 7, k = t & 127;
    float w = (k < 64) ? (W1[(64 + k) * 64 + n] - W1[(128 + k) * 64 + n])
                       : W1[(128 + k) * 64 + n];
    wsWT[t] = f2bf(w);
  }
}

// ---------------- K1: z1[BT][64](bf16) = [h | q*h](bf16) @ Wcomb(bf16) + qW; stats1
__global__ __launch_bounds__(256, 3) void k_gemm1(
    const float* __restrict__ q, const float* __restrict__ hist,
    const u16* __restrict__ wsWT, const float* __restrict__ qW,
    u16* __restrict__ z1, float* __restrict__ part1) {
  __shared__ __align__(16) u16 As[128 * 136];
  __shared__ __align__(16) u16 Ws[64 * 136];
  const int tid = threadIdx.x;
  const int R0 = blockIdx.x * 128;

#pragma unroll
  for (int i = 0; i < 4; i++) {
    int piece = tid + 256 * i;               // 1024 pieces of 8 bf16
    int n = piece >> 4, k8 = piece & 15;
    *(s8v*)(Ws + n * 136 + 8 * k8) = *(const s8v*)(wsWT + n * 128 + 8 * k8);
  }
#pragma unroll
  for (int i = 0; i < 8; i++) {
    int piece = tid + 256 * i;               // 2048 pieces of 4 floats
    int row = piece >> 4, c4 = piece & 15;
    int R = R0 + row;
    int b = (int)((unsigned)R / 200u);
    f4 h4 = *(const f4*)(hist + (size_t)R * 64 + 4 * c4);
    f4 q4 = *(const f4*)(q + (size_t)b * 64 + 4 * c4);
    f4 p4 = h4 * q4;
    s4v hv, pv;
#pragma unroll
    for (int j = 0; j < 4; j++) { hv[j] = (short)f2bf(h4[j]); pv[j] = (short)f2bf(p4[j]); }
    *(s4v*)(As + row * 136 + 4 * c4) = hv;
    *(s4v*)(As + row * 136 + 64 + 4 * c4) = pv;
  }
  __syncthreads();

  const int wv = tid >> 6, lane = tid & 63;
  const int lm16 = lane & 15, quad = lane >> 4;
  f32x4 acc[2][4];
#pragma unroll
  for (int mt = 0; mt < 2; mt++)
#pragma unroll
    for (int nt = 0; nt < 4; nt++) acc[mt][nt] = (f32x4)0.f;

#pragma unroll
  for (int c = 0; c < 4; c++) {
    const int ko = 32 * c + 8 * quad;
    s8v a0 = *(const s8v*)(As + (32 * wv + lm16) * 136 + ko);
    s8v a1 = *(const s8v*)(As + (32 * wv + 16 + lm16) * 136 + ko);
#pragma unroll
    for (int nt = 0; nt < 4; nt++) {
      s8v b8 = *(const s8v*)(Ws + (16 * nt + lm16) * 136 + ko);
      acc[0][nt] = __builtin_amdgcn_mfma_f32_16x16x32_bf16(a0, b8, acc[0][nt], 0, 0, 0);
      acc[1][nt] = __builtin_amdgcn_mfma_f32_16x16x32_bf16(a1, b8, acc[1][nt], 0, 0, 0);
    }
  }
  __syncthreads();

  u16* zs = As;                 // [128][72] bf16
  float* red = (float*)Ws;      // red_s[16][64] | red_q[16][64]
  const int g = wv * 4 + quad;
  float s[4] = {0.f, 0.f, 0.f, 0.f}, sq[4] = {0.f, 0.f, 0.f, 0.f};
#pragma unroll
  for (int mt = 0; mt < 2; mt++)
#pragma unroll
    for (int nt = 0; nt < 4; nt++)
#pragma unroll
      for (int r = 0; r < 4; r++) {
        int row = 32 * wv + 16 * mt + 4 * quad + r;
        int R = R0 + row;
        int b = (int)((unsigned)R / 200u);
        int col = 16 * nt + lm16;
        float v = acc[mt][nt][r] + qW[(size_t)b * 64 + col];
        s[nt] += v; sq[nt] += v * v;
        zs[row * 72 + col] = f2bf(v);
      }
#pragma unroll
  for (int nt = 0; nt < 4; nt++) {
    red[g * 64 + 16 * nt + lm16] = s[nt];
    red[1024 + g * 64 + 16 * nt + lm16] = sq[nt];
  }
  __syncthreads();
#pragma unroll
  for (int i = 0; i < 4; i++) {
    int piece = tid + 256 * i;
    int row = piece >> 3, seg = piece & 7;
    s8v v = *(const s8v*)(zs + row * 72 + 8 * seg);
    *(s8v*)(z1 + (size_t)(R0 + row) * 64 + 8 * seg) = v;
  }
  if (tid < 64) {
    float ss = 0.f, qq = 0.f;
#pragma unroll
    for (int gg = 0; gg < 16; gg++) { ss += red[gg * 64 + tid]; qq += red[1024 + gg * 64 + tid]; }
    part1[(size_t)blockIdx.x * 128 + tid] = ss;
    part1[(size_t)blockIdx.x * 128 + 64 + tid] = qq;
  }
}

// ---------------- finalize: mean/rstd per feature from [block][feature] partials
__global__ __launch_bounds__(256) void k_finalize(
    const float* __restrict__ part, float* __restrict__ statout,
    int nj, int stride, int nb, float invN) {
  const int j = blockIdx.x, tid = threadIdx.x;
  float s = 0.f, qq = 0.f;
  for (int i = tid; i < nb; i += 256) {
    s += part[(size_t)i * stride + j];
    qq += part[(size_t)i * stride + nj + j];
  }
#pragma unroll
  for (int off = 32; off > 0; off >>= 1) {
    s += __shfl_down(s, off);
    qq += __shfl_down(qq, off);
  }
  __shared__ float rs[4], rq[4];
  if ((tid & 63) == 0) { rs[tid >> 6] = s; rq[tid >> 6] = qq; }
  __syncthreads();
  if (tid == 0) {
    s = rs[0] + rs[1] + rs[2] + rs[3];
    qq = rq[0] + rq[1] + rq[2] + rq[3];
    float mean = s * invN;
    float var = qq * invN - mean * mean;
    statout[j] = mean;
    statout[nj + j] = rsqrtf(var + 1e-8f);
  }
}

// ---------------- K2: h = dice1(z1 bf16); z2(bf16) = h @ W2 + b2; stats2
__global__ __launch_bounds__(256) void k_gemm2(
    const u16* __restrict__ z1, const float* __restrict__ W2g,
    const float* __restrict__ b2, const float* __restrict__ alpha1,
    const float* __restrict__ stat1, u16* __restrict__ z2,
    float* __restrict__ part2) {
  __shared__ float W2l[64 * 16];
  __shared__ float cf[208];        // mean[64], rstd[64], alpha[64], b2[16]
  __shared__ float red[256 * 33];
  const int tid = threadIdx.x;
  if (tid < 64) {
    cf[tid] = stat1[tid];
    cf[64 + tid] = stat1[64 + tid];
    cf[128 + tid] = alpha1[tid];
  }
  if (tid < 16) cf[192 + tid] = b2[tid];
#pragma unroll
  for (int i = 0; i < 4; i++) { int idx = tid + 256 * i; W2l[idx] = W2g[idx]; }
  __syncthreads();
  const size_t row = (size_t)blockIdx.x * 256 + tid;
  const u16* zr = z1 + row * 64;
  float acc[16];
#pragma unroll
  for (int j = 0; j < 16; j++) acc[j] = cf[192 + j];
  for (int k0 = 0; k0 < 64; k0 += 8) {
    s8v x8 = *(const s8v*)(zr + k0);
#pragma unroll
    for (int dk = 0; dk < 8; dk++) {
      int k = k0 + dk;
      float x = bf2f((u16)x8[dk]);
      float xn = (x - cf[k]) * cf[64 + k];
      float p = 1.f / (1.f + __expf(-xn));
      float h = x * (p + (1.f - p) * cf[128 + k]);
#pragma unroll
      for (int jc = 0; jc < 4; jc++) {
        f4 w = *(const f4*)(W2l + k * 16 + 4 * jc);
#pragma unroll
        for (int jj = 0; jj < 4; jj++) acc[4 * jc + jj] += h * w[jj];
      }
    }
  }
  s8v o0, o1;
#pragma unroll
  for (int jj = 0; jj < 8; jj++) { o0[jj] = (short)f2bf(acc[jj]); o1[jj] = (short)f2bf(acc[8 + jj]); }
  *(s8v*)(z2 + row * 16) = o0;
  *(s8v*)(z2 + row * 16 + 8) = o1;
#pragma unroll
  for (int j = 0; j < 16; j++) {
    red[tid * 33 + j] = acc[j];
    red[tid * 33 + 16 + j] = acc[j] * acc[j];
  }
  __syncthreads();
  const int f = tid >> 3, sub = tid & 7;   // 32 features x 8 threads
  float s = 0.f;
  for (int g = sub; g < 256; g += 8) s += red[g * 33 + f];
  s += __shfl_down(s, 4, 8);
  s += __shfl_down(s, 2, 8);
  s += __shfl_down(s, 1, 8);
  if (sub == 0) part2[(size_t)blockIdx.x * 32 + f] = s;
}

// ---------------- K3: dice2(z2 bf16) -> inverted-mask softmax -> MFMA score@hist
__global__ __launch_bounds__(256, 3) void k_attn(
    const float* __restrict__ hist, const u16* __restrict__ z2,
    const int* __restrict__ lens, const float* __restrict__ alpha2,
    const float* __restrict__ stat2, float* __restrict__ out) {
  __shared__ float lm[200 * 17];                 // masked logits [t][h]
  __shared__ __align__(16) u16 scb[16 * 232];    // score bf16 [h][t], K-padded to 224
  __shared__ __align__(16) u16 hT[64 * 232];     // hist^T bf16 [e][t]
  __shared__ float cf2[48];
  const int tid = threadIdx.x;
  const int b = blockIdx.x;
  const int L = lens[b];
  if (tid < 16) {
    cf2[tid] = stat2[tid];
    cf2[16 + tid] = stat2[16 + tid];
    cf2[32 + tid] = alpha2[tid];
  }
  __syncthreads();
  // clear K-pad cols t=200..231: 64 scb chunks + 256 hT chunks = 320 total
  // (R4 bug: "else if (tid<320)" only issued 192 hT chunks -> NaN from 0*garbage)
  {
    s8v zz = {0, 0, 0, 0, 0, 0, 0, 0};
    for (int p = tid; p < 320; p += 256) {
      if (p < 64) { int r = p >> 2, c = p & 3; *(s8v*)(scb + r * 232 + 200 + 8 * c) = zz; }
      else { int pp = p - 64; int r = pp >> 2, c = pp & 3; *(s8v*)(hT + r * 232 + 200 + 8 * c) = zz; }
    }
  }
  // stage hist -> LDS transposed bf16 (single global read of the tile)
  const float* hb = hist + (size_t)b * 200 * 64;
#pragma unroll
  for (int i = 0; i < 13; i++) {
    int p = tid + 256 * i;
    if (p < 3200) {
      int t = p >> 4, eq = p & 15;
      f4 h4 = *(const f4*)(hb + t * 64 + 4 * eq);
#pragma unroll
      for (int jj = 0; jj < 4; jj++) hT[(4 * eq + jj) * 232 + t] = f2bf(h4[jj]);
    }
  }
  // dice2 + inverted mask -> lm
  if (tid < 200) {
    const u16* zr = z2 + ((size_t)b * 200 + tid) * 16;
    s8v x0 = *(const s8v*)zr, x1 = *(const s8v*)(zr + 8);
#pragma unroll
    for (int j = 0; j < 16; j++) {
      float x = bf2f((u16)(j < 8 ? x0[j] : x1[j - 8]));
      float xn = (x - cf2[j]) * cf2[16 + j];
      float p = 1.f / (1.f + __expf(-xn));
      float lg = x * (p + (1.f - p) * cf2[32 + j]);
      lm[tid * 17 + j] = (tid < L) ? 1e-9f : lg;   // reference: where(t<len, 1e-9, logits)
    }
  }
  __syncthreads();
  // softmax per h over t (16-lane teams), write bf16 scores
  {
    const int h = tid >> 4, s = tid & 15;
    float v[13];
    float m = -1e30f;
#pragma unroll
    for (int i = 0; i < 13; i++) {
      int t = s + 16 * i;
      float x = (t < 200) ? lm[t * 17 + h] : -1e30f;
      v[i] = x;
      m = fmaxf(m, x);
    }
#pragma unroll
    for (int mk = 8; mk > 0; mk >>= 1) m = fmaxf(m, __shfl_xor(m, mk, 16));
    float sum = 0.f;
#pragma unroll
    for (int i = 0; i < 13; i++) {
      int t = s + 16 * i;
      if (t < 200) { float e = __expf(v[i] - m); v[i] = e; sum += e; }
    }
#pragma unroll
    for (int mk = 8; mk > 0; mk >>= 1) sum += __shfl_xor(sum, mk, 16);
    const float inv = 1.f / sum;
#pragma unroll
    for (int i = 0; i < 13; i++) {
      int t = s + 16 * i;
      if (t < 200) scb[h * 232 + t] = f2bf(v[i] * inv);
    }
  }
  __syncthreads();
  // MFMA: out[16,64] = score[16,224] @ hist[224,64]; wave wv owns e-block 16*wv
  {
    const int wv = tid >> 6, lane = tid & 63;
    const int lm16 = lane & 15, quad = lane >> 4;
    f32x4 acc = {0.f, 0.f, 0.f, 0.f};
#pragma unroll
    for (int c = 0; c < 7; c++) {
      const int ko = 32 * c + 8 * quad;
      s8v a = *(const s8v*)(scb + lm16 * 232 + ko);
      s8v bb = *(const s8v*)(hT + (16 * wv + lm16) * 232 + ko);
      acc = __builtin_amdgcn_mfma_f32_16x16x32_bf16(a, bb, acc, 0, 0, 0);
    }
#pragma unroll
    for (int r = 0; r < 4; r++) {
      int h = 4 * quad + r;
      out[(size_t)b * 1024 + h * 64 + 16 * wv + lm16] = acc[r];
    }
  }
}

extern "C" void kernel_launch(void* const* d_in, const int* in_sizes, int n_in,
                              void* d_out, int out_size, void* d_ws, size_t ws_size,
                              hipStream_t stream) {
  const float* q    = (const float*)d_in[0];
  const float* hist = (const float*)d_in[1];
  const int*   len  = (const int*)d_in[2];
  const float* W1   = (const float*)d_in[3];
  const float* b1   = (const float*)d_in[4];
  const float* al1  = (const float*)d_in[5];
  const float* W2   = (const float*)d_in[6];
  const float* b2   = (const float*)d_in[7];
  const float* al2  = (const float*)d_in[8];
  float* out = (float*)d_out;

  // ws layout (bytes): z1(bf16) | z2(bf16) | qW(f32) | wsWT(bf16) | part1 | part2 | stat1 | stat2
  char* ws = (char*)d_ws;
  u16*   z1    = (u16*)ws;                                   // 52,428,800 B
  u16*   z2    = (u16*)(ws + 52428800);                      // 13,107,200 B
  float* qW    = (float*)(ws + 52428800 + 13107200);         //    524,288 B
  u16*   wsWT  = (u16*)((char*)qW + 524288);                 //     16,384 B
  float* part1 = (float*)((char*)wsWT + 16384);              //  1,638,400 B
  float* part2 = part1 + (size_t)NB1 * 128;                  //    204,800 B
  float* stat1 = part2 + (size_t)NB2 * 32;                   //        512 B
  float* stat2 = stat1 + 128;                                //        128 B
  (void)ws_size; (void)in_sizes; (void)n_in; (void)out_size;

  k_qw<<<dim3(128), dim3(256), 0, stream>>>(q, W1, b1, qW, wsWT);
  k_gemm1<<<dim3(NB1), dim3(256), 0, stream>>>(q, hist, wsWT, qW, z1, part1);
  k_finalize<<<dim3(64), dim3(256), 0, stream>>>(part1, stat1, 64, 128, NB1, 1.f / (float)BT_);
  k_gemm2<<<dim3(NB2), dim3(256), 0, stream>>>(z1, W2, b2, al1, stat1, z2, part2);
  k_finalize<<<dim3(16), dim3(256), 0, stream>>>(part2, stat2, 16, 32, NB2, 1.f / (float)BT_);
  k_attn<<<dim3(B_), dim3(256), 0, stream>>>(hist, z2, len, al2, stat2, out);
}